// Round 3
// baseline (115.107 us; speedup 1.0000x reference)
//
#include <hip/hip_runtime.h>

// SJLT projection: y[b, idx[d,j]] += sign[d,j] * x[b,d]; y *= 0.5
// B=4096, D=16384, P=1024, C=4.
//
// Gather formulation, bf16-staged, 8 rows/block:
//  - x chunk staged in LDS as bf16 granules [d][8 rows] (16 B), XOR-swizzled
//    so staging ds_write_b128 is conflict-free; one random ds_read_b128
//    serves 8 output rows.
//  - per (chunk=2048 d's, col p) entry list: fixed head of 12 ushort entries
//    (dummy = "multiply by 0" flag), rare tail (n>12, ~6%) in spill array.
//  - entry encoding: e = slot<<2 | zero<<1 | sign. slot in [0,2048).
//  - prefetch of next chunk issued right AFTER the barrier -> no vmcnt drain
//    at __syncthreads, loads in flight during the whole gather phase.

#define BATCH     4096
#define ORIG_DIM  16384
#define PROJ_DIM  1024
#define NCHUNK    8
#define CHUNK_D   2048
#define ROWS      8
#define HEAD      12         // processed head entries per list
#define HEAD_STRIDE 16       // stored slots per list row (32 B, aligned)
#define TAILC     20         // tail capacity (entries 12..31); P(n>32|lam=8)~5e-12
#define NLISTS    (NCHUNK * PROJ_DIM)        // 8192
#define DUMMY_W   0x00020002u                // two e=2 entries (zero-flag)

// ws layout (bytes):
//   0      : int flag (1 if rand_indices is int64)
//   64     : int    cnt[NLISTS]                    (32768 B)
//   32832  : ushort head[NLISTS*HEAD_STRIDE]       (262144 B)
//   294976 : ushort tail[NLISTS*TAILC]             (327680 B)
#define WS_CNT_I   16
#define WS_HEAD_B  32832
#define WS_TAIL_B  294976
#define WS_NEEDED  (294976 + 327680)

typedef float f32x2 __attribute__((ext_vector_type(2)));

__global__ void k_init(const unsigned int* __restrict__ idx32,
                       int* __restrict__ ws_i,
                       uint4* __restrict__ head4) {
    int t = blockIdx.x * 256 + threadIdx.x;        // 16384 threads
    head4[t] = uint4{DUMMY_W, DUMMY_W, DUMMY_W, DUMMY_W};   // 16384 x 16B = 256 KB
    if (t < NLISTS / 2)
        ((int2*)(ws_i + WS_CNT_I))[t] = int2{0, 0};
    if (blockIdx.x == 0 && threadIdx.x < 64) {
        unsigned int v = idx32[2 * threadIdx.x + 1];
        unsigned long long b = __ballot(v == 0u);
        if (threadIdx.x == 0) ws_i[0] = (b == 0xFFFFFFFFFFFFFFFFull) ? 1 : 0;
    }
}

__global__ void k_fill(const unsigned int* __restrict__ idx32,
                       const int* __restrict__ signs,
                       int* __restrict__ ws_i,
                       unsigned short* __restrict__ head,
                       unsigned short* __restrict__ tail) {
    int t = blockIdx.x * 256 + threadIdx.x;        // 0..65535 == d*4 + j
    int flag64 = ws_i[0];
    unsigned int p = (flag64 ? idx32[2 * t] : idx32[t]) & (PROJ_DIM - 1);
    int d  = t >> 2;
    unsigned int sg = (signs[t] < 0) ? 1u : 0u;
    int chunk = d >> 11;
    int dl = d & (CHUNK_D - 1);
    unsigned int slot = (unsigned int)dl ^ (((unsigned int)dl >> 3) & 7u);
    unsigned short e = (unsigned short)((slot << 2) | sg);   // zero-flag = 0
    int base = chunk * PROJ_DIM + (int)p;
    int pos = atomicAdd(&ws_i[WS_CNT_I + base], 1);
    if (pos < HEAD)
        head[(size_t)base * HEAD_STRIDE + pos] = e;
    else if (pos < HEAD + TAILC)
        tail[(size_t)base * TAILC + (pos - HEAD)] = e;
}

// process one entry e for column-slot k
#define PROC1(E, K) { \
    unsigned int _e = (unsigned int)(E); \
    uint4 _q = xsb[_e >> 2]; \
    float _sf = (_e & 2u) ? 0.0f : ((_e & 1u) ? -1.0f : 1.0f); \
    f32x2 _sv = { _sf, _sf }; \
    f32x2 _p0 = { __uint_as_float(_q.x << 16), __uint_as_float(_q.x & 0xffff0000u) }; \
    f32x2 _p1 = { __uint_as_float(_q.y << 16), __uint_as_float(_q.y & 0xffff0000u) }; \
    f32x2 _p2 = { __uint_as_float(_q.z << 16), __uint_as_float(_q.z & 0xffff0000u) }; \
    f32x2 _p3 = { __uint_as_float(_q.w << 16), __uint_as_float(_q.w & 0xffff0000u) }; \
    acc[K][0] = __builtin_elementwise_fma(_sv, _p0, acc[K][0]); \
    acc[K][1] = __builtin_elementwise_fma(_sv, _p1, acc[K][1]); \
    acc[K][2] = __builtin_elementwise_fma(_sv, _p2, acc[K][2]); \
    acc[K][3] = __builtin_elementwise_fma(_sv, _p3, acc[K][3]); }

#define PROC2(W, K) { PROC1((W) & 0xffffu, K); PROC1((W) >> 16, K); }

__launch_bounds__(256, 2)
__global__ void k_main(const float* __restrict__ x,
                       const int* __restrict__ cnt,
                       const unsigned short* __restrict__ head,
                       const unsigned short* __restrict__ tail,
                       float* __restrict__ y) {
    __shared__ uint4 xs[2][CHUNK_D];     // 2 x 32 KiB, bf16 granules [d][8 rows]
    const int tid = threadIdx.x;
    const int b0  = blockIdx.x * ROWS;

    const float* xp = x + (size_t)b0 * ORIG_DIM + tid * 8;

    float4 pv[ROWS][2];
    #pragma unroll
    for (int r = 0; r < ROWS; ++r) {
        pv[r][0] = *(const float4*)(xp + (size_t)r * ORIG_DIM);
        pv[r][1] = *(const float4*)(xp + (size_t)r * ORIG_DIM + 4);
    }

    f32x2 acc[4][4];
    #pragma unroll
    for (int k = 0; k < 4; ++k)
        #pragma unroll
        for (int j = 0; j < 4; ++j) acc[k][j] = f32x2{0.f, 0.f};

    for (int ch = 0; ch < NCHUNK; ++ch) {
        uint4* xsb = xs[ch & 1];

        // ---- pack 8 granules (bf16, round-nearest) & ds_write_b128 ----
        #pragma unroll
        for (int i = 0; i < 8; ++i) {
            const int j = i >> 2, m = i & 3;
            #define CMPV(R) (m == 0 ? pv[R][j].x : m == 1 ? pv[R][j].y : \
                             m == 2 ? pv[R][j].z : pv[R][j].w)
            unsigned int u0 = __float_as_uint(CMPV(0)) + 0x8000u;
            unsigned int u1 = __float_as_uint(CMPV(1)) + 0x8000u;
            unsigned int u2 = __float_as_uint(CMPV(2)) + 0x8000u;
            unsigned int u3 = __float_as_uint(CMPV(3)) + 0x8000u;
            unsigned int u4 = __float_as_uint(CMPV(4)) + 0x8000u;
            unsigned int u5 = __float_as_uint(CMPV(5)) + 0x8000u;
            unsigned int u6 = __float_as_uint(CMPV(6)) + 0x8000u;
            unsigned int u7 = __float_as_uint(CMPV(7)) + 0x8000u;
            #undef CMPV
            uint4 w;
            w.x = (u0 >> 16) | (u1 & 0xffff0000u);
            w.y = (u2 >> 16) | (u3 & 0xffff0000u);
            w.z = (u4 >> 16) | (u5 & 0xffff0000u);
            w.w = (u6 >> 16) | (u7 & 0xffff0000u);
            int g = tid * 8 + (i ^ (tid & 7));   // conflict-free write swizzle
            xsb[g] = w;
        }

        __syncthreads();   // nothing outstanding in vmcnt here -> no drain cost

        // ---- issue next chunk's global loads (fly during gather) ----
        if (ch + 1 < NCHUNK) {
            const float* xq = xp + (size_t)(ch + 1) * CHUNK_D;
            #pragma unroll
            for (int r = 0; r < ROWS; ++r) {
                pv[r][0] = *(const float4*)(xq + (size_t)r * ORIG_DIM);
                pv[r][1] = *(const float4*)(xq + (size_t)r * ORIG_DIM + 4);
            }
        }

        // ---- gather: 4 cols/thread, fixed head-12 + rare tail ----
        const int base0 = ch * PROJ_DIM + tid;
        #pragma unroll
        for (int k = 0; k < 4; ++k) {
            int base = base0 + 256 * k;
            const unsigned short* hp = head + (size_t)base * HEAD_STRIDE;
            uint4 h0 = *(const uint4*)hp;
            uint2 h1 = *(const uint2*)(hp + 8);
            int n = cnt[base];
            PROC2(h0.x, k); PROC2(h0.y, k); PROC2(h0.z, k); PROC2(h0.w, k);
            PROC2(h1.x, k); PROC2(h1.y, k);
            if (n > HEAD) {
                const unsigned short* tp = tail + (size_t)base * TAILC;
                int e_end = n < HEAD + TAILC ? n : HEAD + TAILC;
                for (int s = HEAD; s < e_end; ++s)
                    PROC1(tp[s - HEAD], k);
            }
        }
        __syncthreads();
    }

    // ---- epilogue: y = acc * 1/sqrt(4) ----
    #pragma unroll
    for (int k = 0; k < 4; ++k) {
        int p = tid + 256 * k;
        float* yb = y + (size_t)b0 * PROJ_DIM + p;
        #pragma unroll
        for (int j = 0; j < 4; ++j) {
            yb[(size_t)(2 * j)     * PROJ_DIM] = acc[k][j][0] * 0.5f;
            yb[(size_t)(2 * j + 1) * PROJ_DIM] = acc[k][j][1] * 0.5f;
        }
    }
}

// Fallback if workspace is too small: per-row LDS atomic scatter.
__global__ void k_fallback(const float* __restrict__ x,
                           const unsigned int* __restrict__ idx32,
                           const int* __restrict__ signs,
                           float* __restrict__ y) {
    __shared__ float ys[PROJ_DIM];
    __shared__ int sflag;
    int tid = threadIdx.x;
    int b = blockIdx.x;
    if (tid < 64) {
        unsigned int v = idx32[2 * tid + 1];
        unsigned long long bl = __ballot(v == 0u);
        if (tid == 0) sflag = (bl == 0xFFFFFFFFFFFFFFFFull) ? 1 : 0;
    }
    for (int i = tid; i < PROJ_DIM; i += 256) ys[i] = 0.0f;
    __syncthreads();
    int f = sflag;
    const float* xr = x + (size_t)b * ORIG_DIM;
    for (int d = tid; d < ORIG_DIM; d += 256) {
        float v = xr[d];
        #pragma unroll
        for (int j = 0; j < 4; ++j) {
            int t = d * 4 + j;
            unsigned int p = (f ? idx32[2 * t] : idx32[t]) & (PROJ_DIM - 1);
            atomicAdd(&ys[p], (signs[t] < 0) ? -v : v);
        }
    }
    __syncthreads();
    for (int i = tid; i < PROJ_DIM; i += 256)
        y[(size_t)b * PROJ_DIM + i] = ys[i] * 0.5f;
}

extern "C" void kernel_launch(void* const* d_in, const int* in_sizes, int n_in,
                              void* d_out, int out_size, void* d_ws, size_t ws_size,
                              hipStream_t stream) {
    const float*        x     = (const float*)d_in[0];
    const unsigned int* idx32 = (const unsigned int*)d_in[1];
    const int*          signs = (const int*)d_in[2];
    float*              y     = (float*)d_out;

    if (ws_size >= (size_t)WS_NEEDED) {
        int* ws_i = (int*)d_ws;
        unsigned short* head = (unsigned short*)((char*)d_ws + WS_HEAD_B);
        unsigned short* tail = (unsigned short*)((char*)d_ws + WS_TAIL_B);
        k_init<<<64, 256, 0, stream>>>(idx32, ws_i, (uint4*)head);
        k_fill<<<(ORIG_DIM * 4) / 256, 256, 0, stream>>>(idx32, signs, ws_i, head, tail);
        k_main<<<BATCH / ROWS, 256, 0, stream>>>(x, ws_i + WS_CNT_I, head, tail, y);
    } else {
        k_fallback<<<BATCH, 256, 0, stream>>>(x, idx32, signs, y);
    }
}

// Round 4
// 88.697 us; speedup vs baseline: 1.2978x; 1.2978x over previous
//
#include <hip/hip_runtime.h>
#include <hip/hip_fp16.h>

// SJLT projection: y[b, idx[d,j]] += sign[d,j] * x[b,d]; y *= 0.5
// B=4096, D=16384, P=1024, C=4.
//
// Gather formulation, fp16-staged, 8 rows/block, 512-thread blocks:
//  - x chunk staged in LDS as fp16 granules [d][8 rows] (16 B), XOR-swizzled
//    (slot = dl ^ ((dl>>3)&7)) so staging ds_write_b128 hits the 8-lane/bank
//    minimum; one random ds_read_b128 serves 8 output rows.
//  - per (chunk=2048 d's, col p) list: fixed head of 12 ushort entries
//    (dummy = "multiply by 0" flag), rare tail (n>12, ~6%) in spill array.
//  - entry encoding: e = slot<<2 | zero<<1 | sign.
//  - gather math: v_pk_fma_f16 (granule * (+/-1 pair)) -> fp16 pair accum,
//    flushed to fp32 after each chunk (bounded error).
//  - double-buffered LDS, ONE barrier per chunk; next chunk's global loads
//    issued right after the barrier so they are in flight during gather.
//  - 512 threads/block: 2 blocks/CU at 64 KiB LDS -> 16 waves/CU (round 3's
//    256-thr blocks gave only 8 -> latency-bound at 160us).

#define BATCH     4096
#define ORIG_DIM  16384
#define PROJ_DIM  1024
#define NCHUNK    8
#define CHUNK_D   2048
#define ROWS      8
#define HEAD      12
#define HEAD_STRIDE 16       // stored ushorts per list (32 B, aligned)
#define TAILC     20         // entries 12..31; P(n>32|lam=8) ~ 5e-12
#define NLISTS    (NCHUNK * PROJ_DIM)        // 8192
#define DUMMY_W   0x00020002u                // two e=2 entries (zero-flag)

// ws layout (bytes):
//   0      : int flag (1 if rand_indices is int64)
//   64     : int    cnt[NLISTS]                    (32768 B)
//   32832  : ushort head[NLISTS*HEAD_STRIDE]       (262144 B)
//   294976 : ushort tail[NLISTS*TAILC]             (327680 B)
#define WS_CNT_I   16
#define WS_HEAD_B  32832
#define WS_TAIL_B  294976
#define WS_NEEDED  (294976 + 327680)

typedef _Float16 h16x2 __attribute__((ext_vector_type(2)));

__global__ void k_init(const unsigned int* __restrict__ idx32,
                       int* __restrict__ ws_i,
                       uint4* __restrict__ head4) {
    int t = blockIdx.x * 256 + threadIdx.x;        // 16384 threads
    head4[t] = uint4{DUMMY_W, DUMMY_W, DUMMY_W, DUMMY_W};
    if (t < NLISTS / 2)
        ((int2*)(ws_i + WS_CNT_I))[t] = int2{0, 0};
    if (blockIdx.x == 0 && threadIdx.x < 64) {
        unsigned int v = idx32[2 * threadIdx.x + 1];
        unsigned long long b = __ballot(v == 0u);
        if (threadIdx.x == 0) ws_i[0] = (b == 0xFFFFFFFFFFFFFFFFull) ? 1 : 0;
    }
}

__global__ void k_fill(const unsigned int* __restrict__ idx32,
                       const int* __restrict__ signs,
                       int* __restrict__ ws_i,
                       unsigned short* __restrict__ head,
                       unsigned short* __restrict__ tail) {
    int t = blockIdx.x * 256 + threadIdx.x;        // 0..65535 == d*4 + j
    int flag64 = ws_i[0];
    unsigned int p = (flag64 ? idx32[2 * t] : idx32[t]) & (PROJ_DIM - 1);
    int d  = t >> 2;
    unsigned int sg = (signs[t] < 0) ? 1u : 0u;
    int chunk = d >> 11;
    int dl = d & (CHUNK_D - 1);
    unsigned int slot = (unsigned int)dl ^ (((unsigned int)dl >> 3) & 7u);
    unsigned short e = (unsigned short)((slot << 2) | sg);   // zero-flag = 0
    int base = chunk * PROJ_DIM + (int)p;
    int pos = atomicAdd(&ws_i[WS_CNT_I + base], 1);
    if (pos < HEAD)
        head[(size_t)base * HEAD_STRIDE + pos] = e;
    else if (pos < HEAD + TAILC)
        tail[(size_t)base * TAILC + (pos - HEAD)] = e;
}

// process one entry E for column-slot K (8 rows via 4x v_pk_fma_f16)
#define PROC1(E, K) { \
    unsigned int _e = (unsigned int)(E); \
    uint4 _q = xsb[_e >> 2]; \
    unsigned int _s = (_e & 2u) ? 0u \
                    : ((_e & 1u) ? 0xBC00BC00u : 0x3C003C00u); \
    h16x2 _sp = __builtin_bit_cast(h16x2, _s); \
    ha[K][0] = __builtin_elementwise_fma(__builtin_bit_cast(h16x2, _q.x), _sp, ha[K][0]); \
    ha[K][1] = __builtin_elementwise_fma(__builtin_bit_cast(h16x2, _q.y), _sp, ha[K][1]); \
    ha[K][2] = __builtin_elementwise_fma(__builtin_bit_cast(h16x2, _q.z), _sp, ha[K][2]); \
    ha[K][3] = __builtin_elementwise_fma(__builtin_bit_cast(h16x2, _q.w), _sp, ha[K][3]); }

#define PROC2(W, K) { PROC1((W) & 0xffffu, K); PROC1((W) >> 16, K); }

__launch_bounds__(512, 4)
__global__ void k_main(const float* __restrict__ x,
                       const int* __restrict__ cnt,
                       const unsigned short* __restrict__ head,
                       const unsigned short* __restrict__ tail,
                       float* __restrict__ y) {
    __shared__ uint4 xs[2][CHUNK_D];     // 2 x 32 KiB, fp16 granules [d][8 rows]
    const int tid = threadIdx.x;         // 0..511
    const int b0  = blockIdx.x * ROWS;

    const float* xp = x + (size_t)b0 * ORIG_DIM + tid * 4;

    // prefetch chunk 0: one float4 from each of 8 rows at this thread's d-window
    float4 pv[ROWS];
    #pragma unroll
    for (int r = 0; r < ROWS; ++r)
        pv[r] = *(const float4*)(xp + (size_t)r * ORIG_DIM);

    float accf[2][ROWS];
    #pragma unroll
    for (int k = 0; k < 2; ++k)
        #pragma unroll
        for (int r = 0; r < ROWS; ++r) accf[k][r] = 0.f;

    for (int ch = 0; ch < NCHUNK; ++ch) {
        uint4* xsb = xs[ch & 1];

        // ---- pack 4 granules (fp16 RTZ) & ds_write_b128, swizzled ----
        #pragma unroll
        for (int i = 0; i < 4; ++i) {
            #define CMPV(R) (i == 0 ? pv[R].x : i == 1 ? pv[R].y : \
                             i == 2 ? pv[R].z : pv[R].w)
            uint4 w;
            w.x = __builtin_bit_cast(unsigned int, __builtin_amdgcn_cvt_pkrtz(CMPV(0), CMPV(1)));
            w.y = __builtin_bit_cast(unsigned int, __builtin_amdgcn_cvt_pkrtz(CMPV(2), CMPV(3)));
            w.z = __builtin_bit_cast(unsigned int, __builtin_amdgcn_cvt_pkrtz(CMPV(4), CMPV(5)));
            w.w = __builtin_bit_cast(unsigned int, __builtin_amdgcn_cvt_pkrtz(CMPV(6), CMPV(7)));
            #undef CMPV
            int dl = tid * 4 + i;
            int slot = dl ^ ((dl >> 3) & 7);
            xsb[slot] = w;
        }

        __syncthreads();   // nothing outstanding in vmcnt -> no drain cost

        // ---- issue next chunk's global loads (fly during gather) ----
        if (ch + 1 < NCHUNK) {
            const float* xq = xp + (size_t)(ch + 1) * CHUNK_D;
            #pragma unroll
            for (int r = 0; r < ROWS; ++r)
                pv[r] = *(const float4*)(xq + (size_t)r * ORIG_DIM);
        }

        // ---- gather: 2 cols/thread, fixed head-12 + rare tail ----
        h16x2 ha[2][4];
        #pragma unroll
        for (int k = 0; k < 2; ++k)
            #pragma unroll
            for (int j = 0; j < 4; ++j) ha[k][j] = h16x2{0, 0};

        const int base0 = ch * PROJ_DIM + tid;
        int   n[2];
        uint4 h0[2];
        uint2 h1[2];
        #pragma unroll
        for (int k = 0; k < 2; ++k) {
            int base = base0 + 512 * k;
            const unsigned short* hp = head + (size_t)base * HEAD_STRIDE;
            h0[k] = *(const uint4*)hp;
            h1[k] = *(const uint2*)(hp + 8);
            n[k]  = cnt[base];
        }
        #pragma unroll
        for (int k = 0; k < 2; ++k) {
            PROC2(h0[k].x, k); PROC2(h0[k].y, k);
            PROC2(h0[k].z, k); PROC2(h0[k].w, k);
            PROC2(h1[k].x, k); PROC2(h1[k].y, k);
            if (n[k] > HEAD) {
                int base = base0 + 512 * k;
                const unsigned short* tp = tail + (size_t)base * TAILC;
                int e_end = n[k] < HEAD + TAILC ? n[k] : HEAD + TAILC;
                for (int s = HEAD; s < e_end; ++s)
                    PROC1(tp[s - HEAD], k);
            }
        }

        // ---- flush fp16 pair-accumulators into fp32 ----
        #pragma unroll
        for (int k = 0; k < 2; ++k)
            #pragma unroll
            for (int j = 0; j < 4; ++j) {
                accf[k][2 * j]     += (float)ha[k][j][0];
                accf[k][2 * j + 1] += (float)ha[k][j][1];
            }

        __syncthreads();
    }

    // ---- epilogue: y = acc * 1/sqrt(4) ----
    #pragma unroll
    for (int k = 0; k < 2; ++k) {
        int p = tid + 512 * k;
        float* yb = y + (size_t)b0 * PROJ_DIM + p;
        #pragma unroll
        for (int r = 0; r < ROWS; ++r)
            yb[(size_t)r * PROJ_DIM] = accf[k][r] * 0.5f;
    }
}

// Fallback if workspace is too small: per-row LDS atomic scatter.
__global__ void k_fallback(const float* __restrict__ x,
                           const unsigned int* __restrict__ idx32,
                           const int* __restrict__ signs,
                           float* __restrict__ y) {
    __shared__ float ys[PROJ_DIM];
    __shared__ int sflag;
    int tid = threadIdx.x;
    int b = blockIdx.x;
    if (tid < 64) {
        unsigned int v = idx32[2 * tid + 1];
        unsigned long long bl = __ballot(v == 0u);
        if (tid == 0) sflag = (bl == 0xFFFFFFFFFFFFFFFFull) ? 1 : 0;
    }
    for (int i = tid; i < PROJ_DIM; i += 256) ys[i] = 0.0f;
    __syncthreads();
    int f = sflag;
    const float* xr = x + (size_t)b * ORIG_DIM;
    for (int d = tid; d < ORIG_DIM; d += 256) {
        float v = xr[d];
        #pragma unroll
        for (int j = 0; j < 4; ++j) {
            int t = d * 4 + j;
            unsigned int p = (f ? idx32[2 * t] : idx32[t]) & (PROJ_DIM - 1);
            atomicAdd(&ys[p], (signs[t] < 0) ? -v : v);
        }
    }
    __syncthreads();
    for (int i = tid; i < PROJ_DIM; i += 256)
        y[(size_t)b * PROJ_DIM + i] = ys[i] * 0.5f;
}

extern "C" void kernel_launch(void* const* d_in, const int* in_sizes, int n_in,
                              void* d_out, int out_size, void* d_ws, size_t ws_size,
                              hipStream_t stream) {
    const float*        x     = (const float*)d_in[0];
    const unsigned int* idx32 = (const unsigned int*)d_in[1];
    const int*          signs = (const int*)d_in[2];
    float*              y     = (float*)d_out;

    if (ws_size >= (size_t)WS_NEEDED) {
        int* ws_i = (int*)d_ws;
        unsigned short* head = (unsigned short*)((char*)d_ws + WS_HEAD_B);
        unsigned short* tail = (unsigned short*)((char*)d_ws + WS_TAIL_B);
        k_init<<<64, 256, 0, stream>>>(idx32, ws_i, (uint4*)head);
        k_fill<<<(ORIG_DIM * 4) / 256, 256, 0, stream>>>(idx32, signs, ws_i, head, tail);
        k_main<<<BATCH / ROWS, 512, 0, stream>>>(x, ws_i + WS_CNT_I, head, tail, y);
    } else {
        k_fallback<<<BATCH, 256, 0, stream>>>(x, idx32, signs, y);
    }
}

// Round 5
// 83.060 us; speedup vs baseline: 1.3858x; 1.0679x over previous
//
#include <hip/hip_runtime.h>
#include <hip/hip_fp16.h>

// SJLT projection: y[b, idx[d,j]] += sign[d,j] * x[b,d]; y *= 0.5
// B=4096, D=16384, P=1024, C=4.
//
// Gather formulation, fp16-staged, 8 rows/block, 512-thread blocks.
// Round-5 change: fully software-pipelined schedule.
//  - entry lists (head 12 + tail first 8) prefetched ONE CHUNK AHEAD into
//    registers -> gather phase issues no global loads and no waits.
//  - x prefetch issued before the barrier; its waitcnt lands at the next
//    pack, covered by the entire gather phase (previously the head loads,
//    being newer in vmcnt order, forced a full drain before gather).
//  - no cnt[] load in the hot path: tails are dummy-initialized, a register
//    compare on the prefetched tail word decides processing; deep tail
//    (n>=19, ~0.1% of lanes) lazily reads cnt + tail slots 20..35.

#define BATCH     4096
#define ORIG_DIM  16384
#define PROJ_DIM  1024
#define NCHUNK    8
#define CHUNK_D   2048
#define ROWS      8
#define HEAD      12
#define HEAD_STRIDE 16       // stored ushorts per list (32 B)
#define TAILC     24         // tail slots per list (entries 12..35)
#define NLISTS    (NCHUNK * PROJ_DIM)        // 8192
#define DUMMY_W   0x00020002u                // two e=2 entries (zero-flag)

// ws layout (bytes):
//   0      : int flag (1 if rand_indices is int64)
//   64     : int    cnt[NLISTS]                    (32768 B)
//   32832  : ushort head[NLISTS*HEAD_STRIDE]       (262144 B)
//   294976 : ushort tail[NLISTS*TAILC]             (393216 B)
#define WS_CNT_I   16
#define WS_HEAD_B  32832
#define WS_TAIL_B  294976
#define WS_NEEDED  (294976 + 393216)

typedef _Float16 h16x2 __attribute__((ext_vector_type(2)));

__global__ void k_init(const unsigned int* __restrict__ idx32,
                       int* __restrict__ ws_i,
                       uint4* __restrict__ head4,
                       uint2* __restrict__ tail2) {
    int t = blockIdx.x * 256 + threadIdx.x;        // 16384 threads
    head4[t] = uint4{DUMMY_W, DUMMY_W, DUMMY_W, DUMMY_W};
    // tail: NLISTS*TAILC ushorts = 8192*24*2 B = 98304 uint2? (=393216/8)
    #pragma unroll
    for (int i = 0; i < 3; ++i)                    // 16384*3 = 49152 uint2
        tail2[t * 3 + i] = uint2{DUMMY_W, DUMMY_W};
    if (t < NLISTS / 2)
        ((int2*)(ws_i + WS_CNT_I))[t] = int2{0, 0};
    if (blockIdx.x == 0 && threadIdx.x < 64) {
        unsigned int v = idx32[2 * threadIdx.x + 1];
        unsigned long long b = __ballot(v == 0u);
        if (threadIdx.x == 0) ws_i[0] = (b == 0xFFFFFFFFFFFFFFFFull) ? 1 : 0;
    }
}

__global__ void k_fill(const unsigned int* __restrict__ idx32,
                       const int* __restrict__ signs,
                       int* __restrict__ ws_i,
                       unsigned short* __restrict__ head,
                       unsigned short* __restrict__ tail) {
    int t = blockIdx.x * 256 + threadIdx.x;        // 0..65535 == d*4 + j
    int flag64 = ws_i[0];
    unsigned int p = (flag64 ? idx32[2 * t] : idx32[t]) & (PROJ_DIM - 1);
    int d  = t >> 2;
    unsigned int sg = (signs[t] < 0) ? 1u : 0u;
    int chunk = d >> 11;
    int dl = d & (CHUNK_D - 1);
    unsigned int slot = (unsigned int)dl ^ (((unsigned int)dl >> 3) & 7u);
    unsigned short e = (unsigned short)((slot << 2) | sg);   // zero-flag = 0
    int base = chunk * PROJ_DIM + (int)p;
    int pos = atomicAdd(&ws_i[WS_CNT_I + base], 1);
    if (pos < HEAD)
        head[(size_t)base * HEAD_STRIDE + pos] = e;
    else if (pos < HEAD + TAILC)
        tail[(size_t)base * TAILC + (pos - HEAD)] = e;
}

// process one entry E for column-slot K (8 rows via 4x v_pk_fma_f16)
#define PROC1(E, K) { \
    unsigned int _e = (unsigned int)(E); \
    uint4 _q = xsb[_e >> 2]; \
    unsigned int _s = (_e & 2u) ? 0u \
                    : ((_e & 1u) ? 0xBC00BC00u : 0x3C003C00u); \
    h16x2 _sp = __builtin_bit_cast(h16x2, _s); \
    ha[K][0] = __builtin_elementwise_fma(__builtin_bit_cast(h16x2, _q.x), _sp, ha[K][0]); \
    ha[K][1] = __builtin_elementwise_fma(__builtin_bit_cast(h16x2, _q.y), _sp, ha[K][1]); \
    ha[K][2] = __builtin_elementwise_fma(__builtin_bit_cast(h16x2, _q.z), _sp, ha[K][2]); \
    ha[K][3] = __builtin_elementwise_fma(__builtin_bit_cast(h16x2, _q.w), _sp, ha[K][3]); }

#define PROC2(W, K) { PROC1((W) & 0xffffu, K); PROC1((W) >> 16, K); }

__launch_bounds__(512, 4)
__global__ void k_main(const float* __restrict__ x,
                       const int* __restrict__ cnt,
                       const unsigned short* __restrict__ head,
                       const unsigned short* __restrict__ tail,
                       float* __restrict__ y) {
    __shared__ uint4 xs[2][CHUNK_D];     // 2 x 32 KiB, fp16 granules [d][8 rows]
    const int tid = threadIdx.x;         // 0..511
    const int b0  = blockIdx.x * ROWS;

    const float* xp = x + (size_t)b0 * ORIG_DIM + tid * 4;

    uint4 pf_h0[2][2];
    uint2 pf_h1[2][2];
    uint4 pf_t [2][2];
    float4 pv[ROWS];

    // ---- prologue: prefetch chunk-0 lists, then chunk-0 x ----
    #pragma unroll
    for (int k = 0; k < 2; ++k) {
        int base = tid + 512 * k;
        const unsigned short* hp = head + (size_t)base * HEAD_STRIDE;
        pf_h0[0][k] = *(const uint4*)hp;
        pf_h1[0][k] = *(const uint2*)(hp + 8);
        pf_t [0][k] = *(const uint4*)(tail + (size_t)base * TAILC);
    }
    #pragma unroll
    for (int r = 0; r < ROWS; ++r)
        pv[r] = *(const float4*)(xp + (size_t)r * ORIG_DIM);

    float accf[2][ROWS];
    #pragma unroll
    for (int k = 0; k < 2; ++k)
        #pragma unroll
        for (int r = 0; r < ROWS; ++r) accf[k][r] = 0.f;

    #pragma unroll
    for (int ch = 0; ch < NCHUNK; ++ch) {
        const int cur = ch & 1;
        uint4* xsb = xs[cur];

        // ---- pack 4 granules (fp16 RTZ) & ds_write_b128, swizzled ----
        // (this is where the waitcnt for pv lands: covered by prior gather)
        #pragma unroll
        for (int i = 0; i < 4; ++i) {
            #define CMPV(R) (i == 0 ? pv[R].x : i == 1 ? pv[R].y : \
                             i == 2 ? pv[R].z : pv[R].w)
            uint4 w;
            w.x = __builtin_bit_cast(unsigned int, __builtin_amdgcn_cvt_pkrtz(CMPV(0), CMPV(1)));
            w.y = __builtin_bit_cast(unsigned int, __builtin_amdgcn_cvt_pkrtz(CMPV(2), CMPV(3)));
            w.z = __builtin_bit_cast(unsigned int, __builtin_amdgcn_cvt_pkrtz(CMPV(4), CMPV(5)));
            w.w = __builtin_bit_cast(unsigned int, __builtin_amdgcn_cvt_pkrtz(CMPV(6), CMPV(7)));
            #undef CMPV
            int dl = tid * 4 + i;
            int slot = dl ^ ((dl >> 3) & 7);
            xsb[slot] = w;
        }

        // ---- issue NEXT chunk's prefetches (lists then x) ----
        if (ch + 1 < NCHUNK) {
            const int nxt = (ch + 1) & 1;
            #pragma unroll
            for (int k = 0; k < 2; ++k) {
                int base = (ch + 1) * PROJ_DIM + tid + 512 * k;
                const unsigned short* hp = head + (size_t)base * HEAD_STRIDE;
                pf_h0[nxt][k] = *(const uint4*)hp;
                pf_h1[nxt][k] = *(const uint2*)(hp + 8);
                pf_t [nxt][k] = *(const uint4*)(tail + (size_t)base * TAILC);
            }
            const float* xq = xp + (size_t)(ch + 1) * CHUNK_D;
            #pragma unroll
            for (int r = 0; r < ROWS; ++r)
                pv[r] = *(const float4*)(xq + (size_t)r * ORIG_DIM);
        }

        __syncthreads();

        // ---- gather from registers: no global loads, no waits ----
        h16x2 ha[2][4];
        #pragma unroll
        for (int k = 0; k < 2; ++k)
            #pragma unroll
            for (int j = 0; j < 4; ++j) ha[k][j] = h16x2{0, 0};

        #pragma unroll
        for (int k = 0; k < 2; ++k) {
            uint4 h0 = pf_h0[cur][k];
            uint2 h1 = pf_h1[cur][k];
            uint4 t  = pf_t [cur][k];
            PROC2(h0.x, k); PROC2(h0.y, k); PROC2(h0.z, k); PROC2(h0.w, k);
            PROC2(h1.x, k); PROC2(h1.y, k);
            if (t.x != DUMMY_W) { PROC2(t.x, k); }
            if (t.y != DUMMY_W) { PROC2(t.y, k); }
            if (t.z != DUMMY_W) { PROC2(t.z, k); }
            if (t.w != DUMMY_W) {                 // n >= 19: rare deep tail
                PROC2(t.w, k);
                int base = ch * PROJ_DIM + tid + 512 * k;
                int n = cnt[base];
                int e_end = n < HEAD + TAILC ? n : HEAD + TAILC;
                const unsigned short* tp = tail + (size_t)base * TAILC;
                for (int s = HEAD + 8; s < e_end; ++s)
                    PROC1(tp[s - HEAD], k);
            }
        }

        // ---- flush fp16 pair-accumulators into fp32 ----
        #pragma unroll
        for (int k = 0; k < 2; ++k)
            #pragma unroll
            for (int j = 0; j < 4; ++j) {
                accf[k][2 * j]     += (float)ha[k][j][0];
                accf[k][2 * j + 1] += (float)ha[k][j][1];
            }
    }

    // ---- epilogue: y = acc * 1/sqrt(4) ----
    #pragma unroll
    for (int k = 0; k < 2; ++k) {
        int p = tid + 512 * k;
        float* yb = y + (size_t)b0 * PROJ_DIM + p;
        #pragma unroll
        for (int r = 0; r < ROWS; ++r)
            yb[(size_t)r * PROJ_DIM] = accf[k][r] * 0.5f;
    }
}

// Fallback if workspace is too small: per-row LDS atomic scatter.
__global__ void k_fallback(const float* __restrict__ x,
                           const unsigned int* __restrict__ idx32,
                           const int* __restrict__ signs,
                           float* __restrict__ y) {
    __shared__ float ys[PROJ_DIM];
    __shared__ int sflag;
    int tid = threadIdx.x;
    int b = blockIdx.x;
    if (tid < 64) {
        unsigned int v = idx32[2 * tid + 1];
        unsigned long long bl = __ballot(v == 0u);
        if (tid == 0) sflag = (bl == 0xFFFFFFFFFFFFFFFFull) ? 1 : 0;
    }
    for (int i = tid; i < PROJ_DIM; i += 256) ys[i] = 0.0f;
    __syncthreads();
    int f = sflag;
    const float* xr = x + (size_t)b * ORIG_DIM;
    for (int d = tid; d < ORIG_DIM; d += 256) {
        float v = xr[d];
        #pragma unroll
        for (int j = 0; j < 4; ++j) {
            int t = d * 4 + j;
            unsigned int p = (f ? idx32[2 * t] : idx32[t]) & (PROJ_DIM - 1);
            atomicAdd(&ys[p], (signs[t] < 0) ? -v : v);
        }
    }
    __syncthreads();
    for (int i = tid; i < PROJ_DIM; i += 256)
        y[(size_t)b * PROJ_DIM + i] = ys[i] * 0.5f;
}

extern "C" void kernel_launch(void* const* d_in, const int* in_sizes, int n_in,
                              void* d_out, int out_size, void* d_ws, size_t ws_size,
                              hipStream_t stream) {
    const float*        x     = (const float*)d_in[0];
    const unsigned int* idx32 = (const unsigned int*)d_in[1];
    const int*          signs = (const int*)d_in[2];
    float*              y     = (float*)d_out;

    if (ws_size >= (size_t)WS_NEEDED) {
        int* ws_i = (int*)d_ws;
        unsigned short* head = (unsigned short*)((char*)d_ws + WS_HEAD_B);
        unsigned short* tail = (unsigned short*)((char*)d_ws + WS_TAIL_B);
        k_init<<<64, 256, 0, stream>>>(idx32, ws_i, (uint4*)head, (uint2*)tail);
        k_fill<<<(ORIG_DIM * 4) / 256, 256, 0, stream>>>(idx32, signs, ws_i, head, tail);
        k_main<<<BATCH / ROWS, 512, 0, stream>>>(x, ws_i + WS_CNT_I, head, tail, y);
    } else {
        k_fallback<<<BATCH, 256, 0, stream>>>(x, idx32, signs, y);
    }
}